// Round 2
// baseline (668.737 us; speedup 1.0000x reference)
//
#include <hip/hip_runtime.h>
#include <cstdint>

typedef __bf16 bf16_t;
typedef __bf16 bf16x8 __attribute__((ext_vector_type(8)));
typedef __bf16 bf16x4 __attribute__((ext_vector_type(4)));
typedef float  f32x4  __attribute__((ext_vector_type(4)));

#define DEV static __device__ __forceinline__

// global -> LDS async copy, 16B per lane. LDS dest must be wave-uniform base + lane*16.
DEV void load_lds16(const void* g, void* l) {
  __builtin_amdgcn_global_load_lds(
      (__attribute__((address_space(1))) void*)(uintptr_t)g,
      (__attribute__((address_space(3))) void*)l, 16, 0, 0);
}

// ---------------- prep: x fp32 -> bf16 ----------------
__global__ __launch_bounds__(256) void cvt_x_kernel(const float* __restrict__ x,
                                                    bf16_t* __restrict__ xb, int n4) {
  int i = blockIdx.x * 256 + threadIdx.x;
  const int stride = gridDim.x * 256;
  for (; i < n4; i += stride) {
    float4 v = ((const float4*)x)[i];
    bf16x4 o;
    o[0] = (bf16_t)v.x; o[1] = (bf16_t)v.y; o[2] = (bf16_t)v.z; o[3] = (bf16_t)v.w;
    ((bf16x4*)xb)[i] = o;
  }
}

// ---------------- prep: transpose weights to [N][K] bf16, build bias table ----------------
__global__ __launch_bounds__(256) void prep_small_kernel(const float* __restrict__ wqkv,
                                                         const float* __restrict__ wout,
                                                         const float* __restrict__ rel_pos,
                                                         bf16_t* __restrict__ wqkvT,
                                                         bf16_t* __restrict__ woutT,
                                                         float* __restrict__ bias) {
  int i = blockIdx.x * 256 + threadIdx.x;
  if (i < 1152 * 384) {                 // wqkvT[n][k] = wqkv[k][n]
    int n = i / 384, k = i % 384;
    wqkvT[i] = (bf16_t)wqkv[k * 1152 + n];
    return;
  }
  i -= 1152 * 384;
  if (i < 384 * 384) {                  // woutT[n][k] = wout[k][n]
    int n = i / 384, k = i % 384;
    woutT[i] = (bf16_t)wout[k * 384 + n];
    return;
  }
  i -= 384 * 384;
  if (i < 12 * 49 * 49) {               // bias[h][p][q]
    int h = i / 2401, r = i % 2401;
    int p = r / 49, q = r % 49;
    int py = p / 7, px = p % 7, qy = q / 7, qx = q % 7;
    bias[i] = rel_pos[h * 169 + (py - qy + 6) * 13 + (px - qx + 6)];
  }
}

// ---------------- GEMM: C[M][N] = A[M][K] @ BT[N][K]^T + bias ----------------
// 128x128 tile, BK=64, 4 waves (2x2 of 64x64), mfma_f32_16x16x32_bf16.
// M=100352, N%128==0, K%64==0 exactly -> no bounds checks.
template <int N, int K, bool OUT_BF16>
__global__ __launch_bounds__(256) void gemm_kernel(const bf16_t* __restrict__ A,
                                                   const bf16_t* __restrict__ BT,
                                                   const float* __restrict__ bias,
                                                   void* __restrict__ Cout) {
  constexpr int BK = 64;
  __shared__ bf16_t sA[128][BK];
  __shared__ bf16_t sB[128][BK];
  constexpr int NT = N / 128;
  const int mt = blockIdx.x / NT, nt = blockIdx.x % NT;
  const int m0 = mt * 128, n0 = nt * 128;
  const int tid = threadIdx.x;
  const int lane = tid & 63;
  const int wid = tid >> 6;
  const int wr = (wid >> 1) * 64, wc = (wid & 1) * 64;
  const int lr = lane & 15, lg = lane >> 4;
  f32x4 acc[4][4] = {};
  for (int k0 = 0; k0 < K; k0 += BK) {
    #pragma unroll
    for (int i = 0; i < 4; ++i) {
      const int linear = i * 256 + tid;       // 16B unit index
      const int row = linear >> 3, un = linear & 7;
      load_lds16(A  + (size_t)(m0 + row) * K + k0 + un * 8, ((bf16_t*)sA) + (size_t)linear * 8);
      load_lds16(BT + (size_t)(n0 + row) * K + k0 + un * 8, ((bf16_t*)sB) + (size_t)linear * 8);
    }
    __syncthreads();
    #pragma unroll
    for (int k2 = 0; k2 < BK; k2 += 32) {
      bf16x8 af[4], bfr[4];
      #pragma unroll
      for (int mi = 0; mi < 4; ++mi)
        af[mi] = *(const bf16x8*)&sA[wr + mi * 16 + lr][k2 + lg * 8];
      #pragma unroll
      for (int ni = 0; ni < 4; ++ni)
        bfr[ni] = *(const bf16x8*)&sB[wc + ni * 16 + lr][k2 + lg * 8];
      #pragma unroll
      for (int mi = 0; mi < 4; ++mi)
        #pragma unroll
        for (int ni = 0; ni < 4; ++ni)
          acc[mi][ni] = __builtin_amdgcn_mfma_f32_16x16x32_bf16(af[mi], bfr[ni], acc[mi][ni], 0, 0, 0);
    }
    __syncthreads();
  }
  // epilogue: C/D layout col = lane&15, row = (lane>>4)*4 + reg
  #pragma unroll
  for (int ni = 0; ni < 4; ++ni) {
    const int c = n0 + wc + ni * 16 + lr;
    const float bv = bias[c];
    #pragma unroll
    for (int mi = 0; mi < 4; ++mi) {
      const int r0 = m0 + wr + mi * 16 + lg * 4;
      #pragma unroll
      for (int rg = 0; rg < 4; ++rg) {
        const float v = acc[mi][ni][rg] + bv;
        if constexpr (OUT_BF16)
          ((bf16_t*)Cout)[(size_t)(r0 + rg) * N + c] = (bf16_t)v;
        else
          ((float*)Cout)[(size_t)(r0 + rg) * N + c] = v;
      }
    }
  }
}

// ---------------- attention: one wave per (window, head) ----------------
// qkv: [T][1152] bf16 (T = token index in original (b,y,x) order)
// bias: [12][49][49] f32.  out: [T][384] bf16.
__global__ __launch_bounds__(256) void attn_kernel(const bf16_t* __restrict__ qkv,
                                                   const float* __restrict__ bias,
                                                   bf16_t* __restrict__ aout) {
  __shared__ bf16_t P_lds[4][64][64];   // per-wave private P tile (bf16)
  const int tid = threadIdx.x, lane = tid & 63, w = tid >> 6;
  const int pair = blockIdx.x * 4 + w;          // 0..24575
  const int win = pair / 12, h = pair % 12;
  const int b = win >> 6, wy = (win >> 3) & 7, wx = win & 7;
  const int tbase = b * 3136 + wy * 392 + wx * 7;
  const int lr = lane & 15, lg = lane >> 4;
  const float scale = 0.17677669529663687f;   // 32^-0.5

  // Q as A-frag (lane: row=lr, k=lg*8+j), K as B-frag (lane: col=lr, k=lg*8+j) — same load shape
  bf16x8 qf[4], kf[4];
  #pragma unroll
  for (int mi = 0; mi < 4; ++mi) {
    const int p = mi * 16 + lr;
    bf16x8 z = {};
    if (p < 49) {
      const int t = tbase + (p / 7) * 56 + (p % 7);
      const size_t base = (size_t)t * 1152 + h * 32 + lg * 8;
      qf[mi] = *(const bf16x8*)(qkv + base);
      kf[mi] = *(const bf16x8*)(qkv + base + 384);
    } else { qf[mi] = z; kf[mi] = z; }
  }

  f32x4 s[4][4] = {};
  #pragma unroll
  for (int mi = 0; mi < 4; ++mi)
    #pragma unroll
    for (int ni = 0; ni < 4; ++ni)
      s[mi][ni] = __builtin_amdgcn_mfma_f32_16x16x32_bf16(qf[mi], kf[ni], s[mi][ni], 0, 0, 0);

  // scale + rel-pos bias + column mask, then row-wise softmax (16-lane butterfly)
  #pragma unroll
  for (int mi = 0; mi < 4; ++mi) {
    #pragma unroll
    for (int rg = 0; rg < 4; ++rg) {
      const int rr = mi * 16 + lg * 4 + rg;
      const float* brow = bias + (size_t)h * 2401 + rr * 49;
      float vv[4];
      #pragma unroll
      for (int ni = 0; ni < 4; ++ni) {
        const int c = ni * 16 + lr;
        float v = s[mi][ni][rg] * scale;
        if (c < 49) { if (rr < 49) v += brow[c]; }
        else v = -1e30f;
        vv[ni] = v;
      }
      float m = fmaxf(fmaxf(vv[0], vv[1]), fmaxf(vv[2], vv[3]));
      #pragma unroll
      for (int off = 1; off < 16; off <<= 1) m = fmaxf(m, __shfl_xor(m, off, 64));
      float sum = 0.f;
      #pragma unroll
      for (int ni = 0; ni < 4; ++ni) { const float e = __expf(vv[ni] - m); vv[ni] = e; sum += e; }
      #pragma unroll
      for (int off = 1; off < 16; off <<= 1) sum += __shfl_xor(sum, off, 64);
      const float inv = 1.f / sum;
      #pragma unroll
      for (int ni = 0; ni < 4; ++ni) s[mi][ni][rg] = vv[ni] * inv;
    }
  }

  // P (C-layout) -> LDS bf16 so PV can read A-fragments contiguously
  #pragma unroll
  for (int mi = 0; mi < 4; ++mi)
    #pragma unroll
    for (int ni = 0; ni < 4; ++ni)
      #pragma unroll
      for (int rg = 0; rg < 4; ++rg)
        P_lds[w][mi * 16 + lg * 4 + rg][ni * 16 + lr] = (bf16_t)s[mi][ni][rg];
  asm volatile("s_waitcnt lgkmcnt(0)" ::: "memory");

  // O = P @ V : M=64(p), N=32(d), K=64(q) -> 2 k-steps
  f32x4 o[4][2] = {};
  #pragma unroll
  for (int s2 = 0; s2 < 2; ++s2) {
    bf16x8 vfr[2];
    #pragma unroll
    for (int ni = 0; ni < 2; ++ni) {
      #pragma unroll
      for (int j = 0; j < 8; ++j) {
        const int kq = s2 * 32 + lg * 8 + j;
        if (kq < 49) {
          const int t = tbase + (kq / 7) * 56 + (kq % 7);
          vfr[ni][j] = qkv[(size_t)t * 1152 + 768 + h * 32 + ni * 16 + lr];
        } else vfr[ni][j] = (bf16_t)0.f;
      }
    }
    bf16x8 pf[4];
    #pragma unroll
    for (int mi = 0; mi < 4; ++mi)
      pf[mi] = *(const bf16x8*)&P_lds[w][mi * 16 + lr][s2 * 32 + lg * 8];
    #pragma unroll
    for (int mi = 0; mi < 4; ++mi)
      #pragma unroll
      for (int ni = 0; ni < 2; ++ni)
        o[mi][ni] = __builtin_amdgcn_mfma_f32_16x16x32_bf16(pf[mi], vfr[ni], o[mi][ni], 0, 0, 0);
  }

  // store attn out (token order), C-layout rows
  #pragma unroll
  for (int mi = 0; mi < 4; ++mi)
    #pragma unroll
    for (int rg = 0; rg < 4; ++rg) {
      const int p = mi * 16 + lg * 4 + rg;
      if (p < 49) {
        const int t = tbase + (p / 7) * 56 + (p % 7);
        #pragma unroll
        for (int ni = 0; ni < 2; ++ni)
          aout[(size_t)t * 384 + h * 32 + ni * 16 + lr] = (bf16_t)o[mi][ni][rg];
      }
    }
}

extern "C" void kernel_launch(void* const* d_in, const int* in_sizes, int n_in,
                              void* d_out, int out_size, void* d_ws, size_t ws_size,
                              hipStream_t stream) {
  const float* x       = (const float*)d_in[0];
  const float* w_qkv   = (const float*)d_in[1];
  const float* b_qkv   = (const float*)d_in[2];
  const float* rel_pos = (const float*)d_in[3];
  const float* w_out   = (const float*)d_in[4];
  const float* b_out   = (const float*)d_in[5];
  float* out = (float*)d_out;

  // workspace layout (bytes):
  //   qkv bf16   [100352][1152] : 231,211,008
  //   xb  bf16   [100352][384]  :  77,070,336   (re-used as attn_out after GEMM1)
  //   wqkvT bf16 [1152][384]    :     884,736
  //   woutT bf16 [384][384]     :     294,912
  //   bias f32   [12][49][49]   :     115,248
  char* ws = (char*)d_ws;
  const size_t QKV_B = 231211008ull;
  const size_t XB_B  = 77070336ull;
  bf16_t* qkv   = (bf16_t*)ws;
  bf16_t* xb    = (bf16_t*)(ws + QKV_B);
  bf16_t* wqkvT = (bf16_t*)(ws + QKV_B + XB_B);
  bf16_t* woutT = (bf16_t*)(ws + QKV_B + XB_B + 884736);
  float*  bias  = (float*)(ws + QKV_B + XB_B + 884736 + 294912);

  cvt_x_kernel<<<2048, 256, 0, stream>>>(x, xb, 38535168 / 4);
  prep_small_kernel<<<(1152 * 384 + 384 * 384 + 12 * 49 * 49 + 255) / 256, 256, 0, stream>>>(
      w_qkv, w_out, rel_pos, wqkvT, woutT, bias);
  gemm_kernel<1152, 384, true><<<784 * 9, 256, 0, stream>>>(xb, wqkvT, b_qkv, qkv);
  attn_kernel<<<6144, 256, 0, stream>>>(qkv, bias, xb);   // writes attn_out into xb region
  gemm_kernel<384, 384, false><<<784 * 3, 256, 0, stream>>>(xb, woutT, b_out, out);
}

// Round 5
// 661.171 us; speedup vs baseline: 1.0114x; 1.0114x over previous
//
#include <hip/hip_runtime.h>
#include <cstdint>

typedef __bf16 bf16_t;
typedef __bf16 bf16x8 __attribute__((ext_vector_type(8)));
typedef __bf16 bf16x4 __attribute__((ext_vector_type(4)));
typedef float  f32x4  __attribute__((ext_vector_type(4)));

#define DEV static __device__ __forceinline__

// global -> LDS async copy, 16B per lane. LDS dest must be wave-uniform base + lane*16.
DEV void load_lds16(const void* g, void* l) {
  __builtin_amdgcn_global_load_lds(
      (__attribute__((address_space(1))) void*)(uintptr_t)g,
      (__attribute__((address_space(3))) void*)l, 16, 0, 0);
}

// ---------------- prep: x fp32 -> bf16 ----------------
__global__ __launch_bounds__(256) void cvt_x_kernel(const float* __restrict__ x,
                                                    bf16_t* __restrict__ xb, int n4) {
  int i = blockIdx.x * 256 + threadIdx.x;
  const int stride = gridDim.x * 256;
  for (; i < n4; i += stride) {
    float4 v = ((const float4*)x)[i];
    bf16x4 o;
    o[0] = (bf16_t)v.x; o[1] = (bf16_t)v.y; o[2] = (bf16_t)v.z; o[3] = (bf16_t)v.w;
    ((bf16x4*)xb)[i] = o;
  }
}

// ---------------- prep: transpose weights to [N][K] bf16, build bias table ----------------
__global__ __launch_bounds__(256) void prep_small_kernel(const float* __restrict__ wqkv,
                                                         const float* __restrict__ wout,
                                                         const float* __restrict__ rel_pos,
                                                         bf16_t* __restrict__ wqkvT,
                                                         bf16_t* __restrict__ woutT,
                                                         float* __restrict__ bias) {
  int i = blockIdx.x * 256 + threadIdx.x;
  if (i < 1152 * 384) {                 // wqkvT[n][k] = wqkv[k][n]
    int n = i / 384, k = i % 384;
    wqkvT[i] = (bf16_t)wqkv[k * 1152 + n];
    return;
  }
  i -= 1152 * 384;
  if (i < 384 * 384) {                  // woutT[n][k] = wout[k][n]
    int n = i / 384, k = i % 384;
    woutT[i] = (bf16_t)wout[k * 384 + n];
    return;
  }
  i -= 384 * 384;
  if (i < 12 * 49 * 49) {               // bias[h][p][q]
    int h = i / 2401, r = i % 2401;
    int p = r / 49, q = r % 49;
    int py = p / 7, px = p % 7, qy = q / 7, qx = q % 7;
    bias[i] = rel_pos[h * 169 + (py - qy + 6) * 13 + (px - qx + 6)];
  }
}

// qkvw layout: [win][h][part(q,k,v)][49][32] bf16.
// elem offset = win*56448 + (h*3+part)*1568 + q*32 + d
#define WIN_STRIDE 56448
#define HP_STRIDE  1568

// ---------------- GEMM1: qkv = xb @ wqkvT^T + b_qkv, scatter-stored to window layout ----------------
// 128x128 tile, BK=64, 4 waves (2x2 of 64x64). M=100352, N=1152, K=384 exact.
__global__ __launch_bounds__(256) void gemm_qkv_kernel(const bf16_t* __restrict__ A,
                                                       const bf16_t* __restrict__ BT,
                                                       const float* __restrict__ bias,
                                                       bf16_t* __restrict__ qkvw) {
  constexpr int NT = 9, K = 384, BK = 64;
  __shared__ __align__(16) bf16_t smem[16384];   // sA[128][64] | sB[128][64]; epilogue: sC[128][128]
  __shared__ int rowmap[128];
  bf16_t* sA = smem;
  bf16_t* sB = smem + 8192;
  int bid = blockIdx.x;
  bid = (bid & 7) * 882 + (bid >> 3);            // XCD swizzle (7056 = 8*882, bijective)
  const int mt = bid / NT, nt = bid % NT;
  const int m0 = mt * 128, n0 = nt * 128;
  const int tid = threadIdx.x;
  const int lane = tid & 63, wid = tid >> 6;
  const int wr = (wid >> 1) * 64, wc = (wid & 1) * 64;
  const int lr = lane & 15, lg = lane >> 4;

  if (tid < 128) {                               // token -> (win,q) row map (K-loop barrier covers)
    const int t = m0 + tid;
    const int b = t / 3136, r2 = t - b * 3136;
    const int y = r2 / 56, x = r2 - y * 56;
    const int win = b * 64 + (y / 7) * 8 + (x / 7);
    const int q = (y % 7) * 7 + (x % 7);
    rowmap[tid] = win * WIN_STRIDE + q * 32;
  }

  f32x4 acc[4][4] = {};
  for (int k0 = 0; k0 < K; k0 += BK) {
    #pragma unroll
    for (int i = 0; i < 4; ++i) {
      const int linear = i * 256 + tid;          // 16B unit index
      const int row = linear >> 3, un = linear & 7;
      load_lds16(A  + (size_t)(m0 + row) * K + k0 + un * 8, sA + linear * 8);
      load_lds16(BT + (size_t)(n0 + row) * K + k0 + un * 8, sB + linear * 8);
    }
    __syncthreads();
    #pragma unroll
    for (int k2 = 0; k2 < BK; k2 += 32) {
      bf16x8 af[4], bfr[4];
      #pragma unroll
      for (int mi = 0; mi < 4; ++mi)
        af[mi] = *(const bf16x8*)&sA[(wr + mi * 16 + lr) * BK + k2 + lg * 8];
      #pragma unroll
      for (int ni = 0; ni < 4; ++ni)
        bfr[ni] = *(const bf16x8*)&sB[(wc + ni * 16 + lr) * BK + k2 + lg * 8];
      #pragma unroll
      for (int mi = 0; mi < 4; ++mi)
        #pragma unroll
        for (int ni = 0; ni < 4; ++ni)
          acc[mi][ni] = __builtin_amdgcn_mfma_f32_16x16x32_bf16(af[mi], bfr[ni], acc[mi][ni], 0, 0, 0);
    }
    __syncthreads();
  }
  // epilogue: acc -> sC bf16[128][128] (aliases sA/sB; safe after final barrier)
  bf16_t* sC = smem;
  #pragma unroll
  for (int ni = 0; ni < 4; ++ni) {
    const int cl = wc + ni * 16 + lr;
    const float bv = bias[n0 + cl];
    #pragma unroll
    for (int mi = 0; mi < 4; ++mi) {
      const int r0 = wr + mi * 16 + lg * 4;
      #pragma unroll
      for (int rg = 0; rg < 4; ++rg)
        sC[(r0 + rg) * 128 + cl] = (bf16_t)(acc[mi][ni][rg] + bv);
    }
  }
  __syncthreads();
  // coalesced 16B read from sC, 16B scatter-store into window layout
  #pragma unroll
  for (int it = 0; it < 8; ++it) {
    const int linear = it * 256 + tid;           // 2048 units of 16B
    const int row = linear >> 4, u = linear & 15;
    bf16x8 val = *(const bf16x8*)&sC[row * 128 + u * 8];
    const int c0 = n0 + u * 8;
    const int part = c0 >= 768 ? 2 : (c0 >= 384 ? 1 : 0);
    const int cp = c0 - part * 384;
    const int h = cp >> 5, d0 = cp & 31;
    *(bf16x8*)(qkvw + (size_t)rowmap[row] + (h * 3 + part) * HP_STRIDE + d0) = val;
  }
}

// ---------------- GEMM2: out = attn_out @ woutT^T + b_out (fp32, coalesced epilogue) ----------------
__global__ __launch_bounds__(256) void gemm_out_kernel(const bf16_t* __restrict__ A,
                                                       const bf16_t* __restrict__ BT,
                                                       const float* __restrict__ bias,
                                                       float* __restrict__ Cout) {
  constexpr int NT = 3, N = 384, K = 384, BK = 64;
  __shared__ __align__(16) bf16_t smem[16384];   // sA|sB; epilogue: sCf f32[64][128]
  bf16_t* sA = smem;
  bf16_t* sB = smem + 8192;
  float* sCf = (float*)smem;
  int bid = blockIdx.x;
  bid = (bid & 7) * 294 + (bid >> 3);            // XCD swizzle (2352 = 8*294)
  const int mt = bid / NT, nt = bid % NT;
  const int m0 = mt * 128, n0 = nt * 128;
  const int tid = threadIdx.x;
  const int lane = tid & 63, wid = tid >> 6;
  const int wr = (wid >> 1) * 64, wc = (wid & 1) * 64;
  const int lr = lane & 15, lg = lane >> 4;
  f32x4 acc[4][4] = {};
  for (int k0 = 0; k0 < K; k0 += BK) {
    #pragma unroll
    for (int i = 0; i < 4; ++i) {
      const int linear = i * 256 + tid;
      const int row = linear >> 3, un = linear & 7;
      load_lds16(A  + (size_t)(m0 + row) * K + k0 + un * 8, sA + linear * 8);
      load_lds16(BT + (size_t)(n0 + row) * K + k0 + un * 8, sB + linear * 8);
    }
    __syncthreads();
    #pragma unroll
    for (int k2 = 0; k2 < BK; k2 += 32) {
      bf16x8 af[4], bfr[4];
      #pragma unroll
      for (int mi = 0; mi < 4; ++mi)
        af[mi] = *(const bf16x8*)&sA[(wr + mi * 16 + lr) * BK + k2 + lg * 8];
      #pragma unroll
      for (int ni = 0; ni < 4; ++ni)
        bfr[ni] = *(const bf16x8*)&sB[(wc + ni * 16 + lr) * BK + k2 + lg * 8];
      #pragma unroll
      for (int mi = 0; mi < 4; ++mi)
        #pragma unroll
        for (int ni = 0; ni < 4; ++ni)
          acc[mi][ni] = __builtin_amdgcn_mfma_f32_16x16x32_bf16(af[mi], bfr[ni], acc[mi][ni], 0, 0, 0);
    }
    __syncthreads();
  }
  // epilogue in two 64-row halves through LDS (f32), coalesced 16B stores
  #pragma unroll
  for (int hp = 0; hp < 2; ++hp) {
    if ((wid >> 1) == hp) {
      #pragma unroll
      for (int ni = 0; ni < 4; ++ni) {
        const int cl = wc + ni * 16 + lr;
        const float bv = bias[n0 + cl];
        #pragma unroll
        for (int mi = 0; mi < 4; ++mi) {
          const int r0 = mi * 16 + lg * 4;       // local row within the half
          #pragma unroll
          for (int rg = 0; rg < 4; ++rg)
            sCf[(r0 + rg) * 128 + cl] = acc[mi][ni][rg] + bv;
        }
      }
    }
    __syncthreads();
    #pragma unroll
    for (int it = 0; it < 8; ++it) {
      const int linear = it * 256 + tid;         // 2048 units of 16B (4 f32)
      const int row = linear >> 5, u = linear & 31;
      f32x4 v = *(const f32x4*)&sCf[row * 128 + u * 4];
      *(f32x4*)(Cout + (size_t)(m0 + hp * 64 + row) * 384 + n0 + u * 4) = v;
    }
    __syncthreads();
  }
}

// ---------------- attention: one wave per (window, head), window-layout inputs ----------------
__global__ __launch_bounds__(256) void attn_kernel(const bf16_t* __restrict__ qkvw,
                                                   const float* __restrict__ bias,
                                                   bf16_t* __restrict__ aout) {
  __shared__ __align__(16) bf16_t P_lds[4][64][64];   // per-wave P tile
  __shared__ __align__(16) bf16_t v_lds[4][64][32];   // per-wave staged V
  const int tid = threadIdx.x, lane = tid & 63, w = tid >> 6;
  const int pair = blockIdx.x * 4 + w;                // 0..24575
  const int win = pair / 12, h = pair % 12;
  const int b = win >> 6, wy = (win >> 3) & 7, wx = win & 7;
  const int tbase = b * 3136 + wy * 392 + wx * 7;
  const int lr = lane & 15, lg = lane >> 4;
  const float scale = 0.17677669529663687f;           // 32^-0.5
  const bf16_t* base = qkvw + (size_t)win * WIN_STRIDE + (size_t)h * 3 * HP_STRIDE;

  // stage V early (overlaps QK^T + softmax). Rows 49..63 read neighboring finite
  // data; they are multiplied by P==0 exactly, so harmless.
  {
    const bf16_t* vsrc = base + 2 * HP_STRIDE;
    bf16_t* vdst = &v_lds[w][0][0];
    #pragma unroll
    for (int c = 0; c < 4; ++c)
      load_lds16(vsrc + c * 512 + lane * 8, vdst + c * 512 + lane * 8);
  }

  // Q as A-frag (row=lr), K as B-frag (col=lr): both contiguous 16B loads; clamp pad rows
  bf16x8 qf[4], kf[4];
  #pragma unroll
  for (int mi = 0; mi < 4; ++mi) {
    const int p = mi * 16 + lr;
    const int pq = p < 49 ? p : 48;
    qf[mi] = *(const bf16x8*)(base + pq * 32 + lg * 8);
    kf[mi] = *(const bf16x8*)(base + HP_STRIDE + pq * 32 + lg * 8);
  }

  f32x4 s[4][4] = {};
  #pragma unroll
  for (int mi = 0; mi < 4; ++mi)
    #pragma unroll
    for (int ni = 0; ni < 4; ++ni)
      s[mi][ni] = __builtin_amdgcn_mfma_f32_16x16x32_bf16(qf[mi], kf[ni], s[mi][ni], 0, 0, 0);

  // scale + rel-pos bias + column mask, row-wise softmax (16-lane butterfly)
  #pragma unroll
  for (int mi = 0; mi < 4; ++mi) {
    #pragma unroll
    for (int rg = 0; rg < 4; ++rg) {
      const int rr = mi * 16 + lg * 4 + rg;
      const float* brow = bias + (size_t)h * 2401 + rr * 49;
      float vv[4];
      #pragma unroll
      for (int ni = 0; ni < 4; ++ni) {
        const int c = ni * 16 + lr;
        float v = s[mi][ni][rg] * scale;
        if (c < 49) { if (rr < 49) v += brow[c]; }
        else v = -1e30f;
        vv[ni] = v;
      }
      float m = fmaxf(fmaxf(vv[0], vv[1]), fmaxf(vv[2], vv[3]));
      #pragma unroll
      for (int off = 1; off < 16; off <<= 1) m = fmaxf(m, __shfl_xor(m, off, 64));
      float sum = 0.f;
      #pragma unroll
      for (int ni = 0; ni < 4; ++ni) { const float e = __expf(vv[ni] - m); vv[ni] = e; sum += e; }
      #pragma unroll
      for (int off = 1; off < 16; off <<= 1) sum += __shfl_xor(sum, off, 64);
      const float inv = 1.f / sum;
      #pragma unroll
      for (int ni = 0; ni < 4; ++ni) s[mi][ni][rg] = vv[ni] * inv;
    }
  }

  // P (C-layout) -> LDS bf16 so PV reads A-fragments contiguously
  #pragma unroll
  for (int mi = 0; mi < 4; ++mi)
    #pragma unroll
    for (int ni = 0; ni < 4; ++ni)
      #pragma unroll
      for (int rg = 0; rg < 4; ++rg)
        P_lds[w][mi * 16 + lg * 4 + rg][ni * 16 + lr] = (bf16_t)s[mi][ni][rg];

  asm volatile("s_waitcnt vmcnt(0) lgkmcnt(0)" ::: "memory");   // V staged + P visible
  __builtin_amdgcn_sched_barrier(0);

  // O = P @ V : M=64(p), N=32(d), K=64(q); V columns via LDS transpose-read
  f32x4 o[4][2] = {};
  #pragma unroll
  for (int s2 = 0; s2 < 2; ++s2) {
    bf16x8 vfr[2];
    #pragma unroll
    for (int ni = 0; ni < 2; ++ni)
      #pragma unroll
      for (int j = 0; j < 8; ++j)
        vfr[ni][j] = v_lds[w][s2 * 32 + lg * 8 + j][ni * 16 + lr];
    bf16x8 pf[4];
    #pragma unroll
    for (int mi = 0; mi < 4; ++mi)
      pf[mi] = *(const bf16x8*)&P_lds[w][mi * 16 + lr][s2 * 32 + lg * 8];
    #pragma unroll
    for (int mi = 0; mi < 4; ++mi)
      #pragma unroll
      for (int ni = 0; ni < 2; ++ni)
        o[mi][ni] = __builtin_amdgcn_mfma_f32_16x16x32_bf16(pf[mi], vfr[ni], o[mi][ni], 0, 0, 0);
  }

  // store attn out in token order (feeds GEMM2's linear A loads)
  #pragma unroll
  for (int mi = 0; mi < 4; ++mi)
    #pragma unroll
    for (int rg = 0; rg < 4; ++rg) {
      const int p = mi * 16 + lg * 4 + rg;
      if (p < 49) {
        const int t = tbase + (p / 7) * 56 + (p % 7);
        #pragma unroll
        for (int ni = 0; ni < 2; ++ni)
          aout[(size_t)t * 384 + h * 32 + ni * 16 + lr] = (bf16_t)o[mi][ni][rg];
      }
    }
}

extern "C" void kernel_launch(void* const* d_in, const int* in_sizes, int n_in,
                              void* d_out, int out_size, void* d_ws, size_t ws_size,
                              hipStream_t stream) {
  const float* x       = (const float*)d_in[0];
  const float* w_qkv   = (const float*)d_in[1];
  const float* b_qkv   = (const float*)d_in[2];
  const float* rel_pos = (const float*)d_in[3];
  const float* w_out   = (const float*)d_in[4];
  const float* b_out   = (const float*)d_in[5];
  float* out = (float*)d_out;

  // workspace layout (total 309,576,240 B — same footprint as the proven round-2 layout):
  //   qkvw bf16 [2048][12][3][49][32] : 231,211,008  (window-gathered Q,K,V)
  //   xb   bf16 [100352][384]         :  77,070,336  (GEMM1 A; re-used as attn_out)
  //   wqkvT bf16 [1152][384]          :     884,736
  //   woutT bf16 [384][384]           :     294,912
  //   bias  f32  [12][49][49]         :     115,248
  char* ws = (char*)d_ws;
  const size_t QKVW_B = 231211008ull;
  const size_t XB_B   = 77070336ull;
  bf16_t* qkvw  = (bf16_t*)ws;
  bf16_t* xb    = (bf16_t*)(ws + QKVW_B);
  bf16_t* wqkvT = (bf16_t*)(ws + QKVW_B + XB_B);
  bf16_t* woutT = (bf16_t*)(ws + QKVW_B + XB_B + 884736);
  float*  bias  = (float*)(ws + QKVW_B + XB_B + 884736 + 294912);

  cvt_x_kernel<<<2048, 256, 0, stream>>>(x, xb, 38535168 / 4);
  prep_small_kernel<<<(1152 * 384 + 384 * 384 + 12 * 49 * 49 + 255) / 256, 256, 0, stream>>>(
      w_qkv, w_out, rel_pos, wqkvT, woutT, bias);
  gemm_qkv_kernel<<<784 * 9, 256, 0, stream>>>(xb, wqkvT, b_qkv, qkvw);
  attn_kernel<<<6144, 256, 0, stream>>>(qkvw, bias, xb);   // attn_out into xb region
  gemm_out_kernel<<<784 * 3, 256, 0, stream>>>(xb, woutT, b_out, out);
}